// Round 1
// baseline (206.871 us; speedup 1.0000x reference)
//
#include <hip/hip_runtime.h>
#include <math.h>

#define IMG_H 512
#define IMG_W 512
#define IMG_C 3
#define IMG_N 32
#define TH 32
#define TW 64

// Pass 1: cmax over channels of (1-img)  ==  1 - min over channels of img,
// then horizontal sliding max of window 35 (centered, -inf padding).
// Decomposition: win35(x) = max_{k=-3..3} win5(x+5k).
__global__ __launch_bounds__(256) void dc_rowmax(const float* __restrict__ img,
                                                 float* __restrict__ rowmax) {
    __shared__ float rowbuf[546];   // x in [-17, 528]
    __shared__ float tmp5[542];     // win5 centers in [-15, 526]
    const int b = blockIdx.x;       // n*512 + y
    const int n = b >> 9;
    const int y = b & 511;
    const float* base = img + (size_t)n * (IMG_C * IMG_H * IMG_W) + (size_t)y * IMG_W;
    const int tid = threadIdx.x;

    for (int i = tid; i < 546; i += 256) {
        int x = i - 17;
        float v = -INFINITY;
        if (x >= 0 && x < IMG_W) {
            float a0 = base[x];
            float a1 = base[x + IMG_H * IMG_W];
            float a2 = base[x + 2 * IMG_H * IMG_W];
            v = 1.0f - fminf(a0, fminf(a1, a2));
        }
        rowbuf[i] = v;
    }
    __syncthreads();
    for (int i = tid; i < 542; i += 256) {
        // tmp5[i] covers original x-range [i-17, i-13] -> win5 centered at i-15
        float m = rowbuf[i];
        m = fmaxf(m, rowbuf[i + 1]);
        m = fmaxf(m, rowbuf[i + 2]);
        m = fmaxf(m, rowbuf[i + 3]);
        m = fmaxf(m, rowbuf[i + 4]);
        tmp5[i] = m;
    }
    __syncthreads();
    float* orow = rowmax + (size_t)b * IMG_W;
    for (int x = tid; x < IMG_W; x += 256) {
        // centers x+5k-15, k=0..6 -> tmp5[x + 5k]
        float m = tmp5[x];
        #pragma unroll
        for (int k = 1; k < 7; ++k) m = fmaxf(m, tmp5[x + 5 * k]);
        orow[x] = m;
    }
}

// Pass 2: vertical sliding max of window 35 over rowmax, then mean reduction.
// Tile: TW=64 cols x TH=32 output rows per block; input halo 17 rows each side.
__global__ __launch_bounds__(256) void dc_colmax_reduce(const float* __restrict__ rowmax,
                                                        float* __restrict__ out) {
    __shared__ float inb[66 * 64];   // rows y0-17 .. y0+TH+16
    __shared__ float tmp5[62 * 64];  // win5 centers y0-15 .. y0+TH+14
    __shared__ float wsum[4];
    const int b = blockIdx.x;        // n*(16*8) + ty*8 + tx
    const int tx = b & 7;
    const int ty = (b >> 3) & 15;
    const int n = b >> 7;
    const int y0 = ty * TH;
    const int x0 = tx * TW;
    const int tid = threadIdx.x;
    const float* base = rowmax + (size_t)n * IMG_H * IMG_W + x0;

    for (int i = tid; i < 66 * 64; i += 256) {
        int r = i >> 6, c = i & 63;
        int gy = y0 - 17 + r;
        inb[i] = (gy >= 0 && gy < IMG_H) ? base[(size_t)gy * IMG_W + c] : -INFINITY;
    }
    __syncthreads();
    for (int i = tid; i < 62 * 64; i += 256) {
        float m = inb[i];
        m = fmaxf(m, inb[i + 64]);
        m = fmaxf(m, inb[i + 128]);
        m = fmaxf(m, inb[i + 192]);
        m = fmaxf(m, inb[i + 256]);
        tmp5[i] = m;
    }
    __syncthreads();
    float s = 0.0f;
    for (int i = tid; i < TH * TW; i += 256) {
        // output row r = i>>6: needs tmp5 rows r+5k, k=0..6 -> tmp5[i + 320k]
        float m = tmp5[i];
        #pragma unroll
        for (int k = 1; k < 7; ++k) m = fmaxf(m, tmp5[i + 320 * k]);
        s += fabsf(m);
    }
    // wave64 reduce, then cross-wave via LDS
    #pragma unroll
    for (int off = 32; off > 0; off >>= 1) s += __shfl_down(s, off);
    const int lane = tid & 63, wv = tid >> 6;
    if (lane == 0) wsum[wv] = s;
    __syncthreads();
    if (tid == 0) {
        float t = wsum[0] + wsum[1] + wsum[2] + wsum[3];
        atomicAdd(out, t * (1.0f / (float)(IMG_N * IMG_H * IMG_W)));
    }
}

extern "C" void kernel_launch(void* const* d_in, const int* in_sizes, int n_in,
                              void* d_out, int out_size, void* d_ws, size_t ws_size,
                              hipStream_t stream) {
    const float* img = (const float*)d_in[0];
    float* out = (float*)d_out;
    float* rowmax = (float*)d_ws;   // 32*512*512 floats = 33.5 MB scratch

    hipMemsetAsync(d_out, 0, sizeof(float), stream);
    dc_rowmax<<<IMG_N * IMG_H, 256, 0, stream>>>(img, rowmax);
    dc_colmax_reduce<<<IMG_N * (IMG_H / TH) * (IMG_W / TW), 256, 0, stream>>>(rowmax, out);
}

// Round 2
// 162.696 us; speedup vs baseline: 1.2715x; 1.2715x over previous
//
#include <hip/hip_runtime.h>
#include <math.h>

#define IMG_H 512
#define IMG_W 512
#define NIMG 32
#define R_ROWS 4        // rows per block in pass 1
#define RB_W 552        // rowbuf padded width; x -> index 20+x, halo [3..19] & [532..551]
#define T5_W 544        // tmp5 padded width (542 used)
#define YC 64           // output rows per thread/block in pass 2

// ---------------- Pass 1: cmax + horizontal win35 (5 then 7-tap stride-5) -------------
__global__ __launch_bounds__(256) void dc_rowmax(const float* __restrict__ img,
                                                 float* __restrict__ rowmax) {
    __shared__ float rowbuf[R_ROWS][RB_W];
    __shared__ float tmp5[R_ROWS][T5_W];
    const int b = blockIdx.x;            // n*128 + ytile
    const int n = b >> 7;
    const int y0 = (b & 127) * R_ROWS;
    const int tid = threadIdx.x;

    // halo fill: indices [0,20) and [532,552) per row = 40 each
    for (int i = tid; i < R_ROWS * 40; i += 256) {
        int r = i / 40, j = i % 40;
        int idx = (j < 20) ? j : (512 + j);  // j<20 -> [0,20); else 532..551
        rowbuf[r][idx] = -INFINITY;
    }
    // main fill: 512 float4 positions (4 rows x 128), cmax = 1 - min over 3 channels
    const float4* imgb = (const float4*)(img + ((size_t)n * 3 * IMG_H + y0) * IMG_W);
    for (int p = tid; p < R_ROWS * 128; p += 256) {
        int r = p >> 7, xq = p & 127;
        int o = r * 128 + xq;
        float4 a = imgb[o];
        float4 b4 = imgb[65536 + o];     // + H*W/4
        float4 c4 = imgb[131072 + o];    // + 2*H*W/4
        float4 m;
        m.x = 1.0f - fminf(a.x, fminf(b4.x, c4.x));
        m.y = 1.0f - fminf(a.y, fminf(b4.y, c4.y));
        m.z = 1.0f - fminf(a.z, fminf(b4.z, c4.z));
        m.w = 1.0f - fminf(a.w, fminf(b4.w, c4.w));
        *(float4*)&rowbuf[r][20 + 4 * xq] = m;   // (20+4xq)*4B is 16B-aligned
    }
    __syncthreads();
    // win5: tmp5[r][i] = max(rowbuf[r][i+3 .. i+7])  (window start x = i-17)
    #pragma unroll
    for (int r = 0; r < R_ROWS; ++r)
        for (int i = tid; i < 542; i += 256) {
            float m = rowbuf[r][i + 3];
            m = fmaxf(m, rowbuf[r][i + 4]);
            m = fmaxf(m, rowbuf[r][i + 5]);
            m = fmaxf(m, rowbuf[r][i + 6]);
            m = fmaxf(m, rowbuf[r][i + 7]);
            tmp5[r][i] = m;
        }
    __syncthreads();
    // win35: out[x] = max_k tmp5[x+5k], k=0..6
    float* orow = rowmax + ((size_t)n * IMG_H + y0) * IMG_W;
    #pragma unroll
    for (int r = 0; r < R_ROWS; ++r)
        for (int x = tid; x < IMG_W; x += 256) {
            float m = tmp5[r][x];
            #pragma unroll
            for (int k = 1; k < 7; ++k) m = fmaxf(m, tmp5[r][x + 5 * k]);
            orow[(size_t)r * IMG_W + x] = m;
        }
}

// -------- Pass 2: vertical win35 via register streaming (no LDS), + reduction --------
__global__ __launch_bounds__(256) void dc_colmax(const float* __restrict__ rowmax,
                                                 float* __restrict__ out) {
    __shared__ float wsum[4];
    const int b = blockIdx.x;            // n*16 + yt*2 + xt
    const int xt = b & 1;
    const int yt = (b >> 1) & 7;
    const int n = b >> 4;
    const int x = xt * 256 + (int)threadIdx.x;
    const int y0 = yt * YC;
    const float* col = rowmax + (size_t)n * IMG_H * IMG_W + x;

    float A[YC];
    float r0 = 0.f, r1 = 0.f, r2 = 0.f, r3 = 0.f, r4 = 0.f;
    float s = 0.0f;
    #pragma unroll
    for (int m = 0; m < YC + 34; ++m) {
        int gy = y0 - 17 + m;
        float v = (gy >= 0 && gy < IMG_H) ? col[(size_t)gy * IMG_W] : -INFINITY;
        r0 = r1; r1 = r2; r2 = r3; r3 = r4; r4 = v;   // renamed away by unroll
        if (m >= 4) {
            const int mg = m - 4;                     // g-stream index 0..YC+29
            float g = fmaxf(fmaxf(fmaxf(r0, r1), fmaxf(r2, r3)), r4);
            #pragma unroll
            for (int k = 0; k < 7; ++k) {
                const int i = mg - 5 * k;             // compile-time after unroll
                if (i >= 0 && i < YC) {
                    if (i == mg) A[i] = g;            // first touch (k==0)
                    else A[i] = fmaxf(A[i], g);
                }
            }
            if (mg >= 30) s += fabsf(A[mg - 30]);     // output y0+mg-30 complete
        }
    }
    // wave64 reduce then cross-wave
    #pragma unroll
    for (int off = 32; off > 0; off >>= 1) s += __shfl_down(s, off);
    const int lane = (int)threadIdx.x & 63, wv = (int)threadIdx.x >> 6;
    if (lane == 0) wsum[wv] = s;
    __syncthreads();
    if (threadIdx.x == 0) {
        float t = wsum[0] + wsum[1] + wsum[2] + wsum[3];
        atomicAdd(out, t * (1.0f / ((float)NIMG * IMG_H * IMG_W)));
    }
}

extern "C" void kernel_launch(void* const* d_in, const int* in_sizes, int n_in,
                              void* d_out, int out_size, void* d_ws, size_t ws_size,
                              hipStream_t stream) {
    const float* img = (const float*)d_in[0];
    float* out = (float*)d_out;
    float* rowmax = (float*)d_ws;    // 32*512*512 floats = 33.5 MB scratch

    hipMemsetAsync(d_out, 0, sizeof(float), stream);
    dc_rowmax<<<NIMG * (IMG_H / R_ROWS), 256, 0, stream>>>(img, rowmax);
    dc_colmax<<<NIMG * 8 * 2, 256, 0, stream>>>(rowmax, out);
}